// Round 1
// baseline (227.756 us; speedup 1.0000x reference)
//
#include <hip/hip_runtime.h>
#include <hip/hip_bf16.h>
#include <stdint.h>

#define ALPHA 0.2f

typedef __attribute__((ext_vector_type(8))) short bf16x8;
typedef __attribute__((ext_vector_type(4))) float f32x4;

__device__ __forceinline__ short f2bf(float f) {
    union { float f; uint32_t u; } c; c.f = f;
    uint32_t u = c.u + 0x7FFF + ((c.u >> 16) & 1);   // round-to-nearest-even
    return (short)(u >> 16);
}

// ---------------------------------------------------------------------------
// Kernel 0: pack adj (int32 0/1, [2048][2048]) into bitmask, 1 bit per edge.
// wave lane L ballot -> bit L of word. 65536 uint64 words total.
// ---------------------------------------------------------------------------
__global__ __launch_bounds__(256) void pack_adj_kernel(
        const int* __restrict__ adj, unsigned long long* __restrict__ bits) {
    int idx = blockIdx.x * 256 + threadIdx.x;
    int lane = threadIdx.x & 63;
    unsigned long long m = __ballot(adj[idx] > 0);
    if (lane == 0) bits[idx >> 6] = m;
}

// ---------------------------------------------------------------------------
// Kernel 1: Wh = h @ W (bf16 MFMA, fp32 accum); epilogue computes
//   s1 = Wh·a1, s2 = Wh·a2 (fp32) and writes WhT_bf16 [b][f=128][j=2048].
// Grid: 256 blocks x 256 threads; wave w handles 16 rows of (B*N = 16384).
// ---------------------------------------------------------------------------
__global__ __launch_bounds__(256) void wh_kernel(
        const float* __restrict__ h, const float* __restrict__ W,
        const float* __restrict__ a, short* __restrict__ whT,
        float* __restrict__ s1g, float* __restrict__ s2g) {
    __shared__ char smem[128 * 136 * 2];           // 34816 B, reused
    short (*WT)[136] = reinterpret_cast<short(*)[136]>(smem); // W^T bf16, [f][k] pad->136

    int tid = threadIdx.x;
    // cooperative transpose W (fp32 [k][f]) -> WT bf16 [f][k]
    #pragma unroll
    for (int it = 0; it < 16; ++it) {
        int idx = it * 256 + tid;                  // 4096 float4
        int k  = idx >> 5;                         // 32 float4 per k-row
        int f4 = (idx & 31) * 4;
        float4 w4 = reinterpret_cast<const float4*>(W)[idx];
        WT[f4 + 0][k] = f2bf(w4.x);
        WT[f4 + 1][k] = f2bf(w4.y);
        WT[f4 + 2][k] = f2bf(w4.z);
        WT[f4 + 3][k] = f2bf(w4.w);
    }
    __syncthreads();

    int w = tid >> 6, lane = tid & 63;
    int q = lane >> 4, n = lane & 15;
    int rb = blockIdx.x * 64 + w * 16;             // global row base (b*2048+j)
    int row = rb + n;                              // A-operand m = lane&15

    f32x4 acc[8] = {};
    #pragma unroll
    for (int kc = 0; kc < 4; ++kc) {
        const float* hp = h + (size_t)row * 128 + kc * 32 + q * 8;
        float4 h0 = reinterpret_cast<const float4*>(hp)[0];
        float4 h1 = reinterpret_cast<const float4*>(hp)[1];
        bf16x8 afrag;
        afrag[0] = f2bf(h0.x); afrag[1] = f2bf(h0.y);
        afrag[2] = f2bf(h0.z); afrag[3] = f2bf(h0.w);
        afrag[4] = f2bf(h1.x); afrag[5] = f2bf(h1.y);
        afrag[6] = f2bf(h1.z); afrag[7] = f2bf(h1.w);
        #pragma unroll
        for (int t = 0; t < 8; ++t) {
            bf16x8 bfrag = *reinterpret_cast<const bf16x8*>(&WT[t * 16 + n][kc * 32 + q * 8]);
            acc[t] = __builtin_amdgcn_mfma_f32_16x16x32_bf16(afrag, bfrag, acc[t], 0, 0, 0);
        }
    }

    // ---- epilogue 1: s1/s2.  C layout: col = lane&15 (+16t), row = q*4+r.
    float p1[4] = {0.f, 0.f, 0.f, 0.f}, p2[4] = {0.f, 0.f, 0.f, 0.f};
    #pragma unroll
    for (int t = 0; t < 8; ++t) {
        int c = t * 16 + n;
        float a1c = a[c], a2c = a[128 + c];
        #pragma unroll
        for (int r = 0; r < 4; ++r) {
            p1[r] += acc[t][r] * a1c;
            p2[r] += acc[t][r] * a2c;
        }
    }
    #pragma unroll
    for (int d = 1; d < 16; d <<= 1) {
        #pragma unroll
        for (int r = 0; r < 4; ++r) {
            p1[r] += __shfl_xor(p1[r], d);
            p2[r] += __shfl_xor(p2[r], d);
        }
    }
    if (n == 0) {
        #pragma unroll
        for (int r = 0; r < 4; ++r) {
            int rr = rb + q * 4 + r;
            s1g[rr] = p1[r];
            s2g[rr] = p2[r];
        }
    }

    // ---- epilogue 2: WhT_bf16 via per-wave LDS transpose (stride 24 shorts).
    __syncthreads();                               // all waves done with WT
    short* tr = reinterpret_cast<short*>(smem) + w * 3072;  // 128 x 24 shorts
    #pragma unroll
    for (int t = 0; t < 8; ++t)
        #pragma unroll
        for (int r = 0; r < 4; ++r)
            tr[(t * 16 + n) * 24 + q * 4 + r] = f2bf(acc[t][r]);
    __syncthreads();

    int bb = rb >> 11;
    int jrow = rb & 2047;
    #pragma unroll
    for (int half = 0; half < 2; ++half) {
        int f = half * 64 + lane;
        bf16x8 v0 = *reinterpret_cast<const bf16x8*>(tr + f * 24);
        bf16x8 v1 = *reinterpret_cast<const bf16x8*>(tr + f * 24 + 8);
        size_t o = ((size_t)(bb * 128 + f) * 2048) + jrow;
        *reinterpret_cast<bf16x8*>(whT + o)     = v0;   // j 0..7
        *reinterpret_cast<bf16x8*>(whT + o + 8) = v1;   // j 8..15
    }
}

// ---------------------------------------------------------------------------
// Kernel 2: fused masked-softmax attention + PV, single pass over j.
// Grid: 256 blocks (b, itile of 64 rows) x 4 waves (16 rows each).
// Per j-chunk(32): P computed in A-frag layout in regs, B-frags from WhT.
// Unnormalized accumulate; divide by row-denominator at the end.
// ---------------------------------------------------------------------------
__global__ __launch_bounds__(256) void attn_kernel(
        const short* __restrict__ whT, const float* __restrict__ s1g,
        const float* __restrict__ s2g, const uint8_t* __restrict__ adjb,
        float* __restrict__ out) {
    int w = threadIdx.x >> 6, lane = threadIdx.x & 63;
    int q = lane >> 4, n = lane & 15;
    int b  = blockIdx.x >> 5;
    int ib = (blockIdx.x & 31) * 64 + w * 16;
    int row = ib + n;                              // P's m = lane&15

    float s1v = s1g[b * 2048 + row];
    const float*   s2b  = s2g + b * 2048;
    const short*   whTb = whT + (size_t)b * 128 * 2048;
    const uint8_t* adjr = adjb + (size_t)row * 256;   // 2048 bits / row

    f32x4 acc[8] = {};
    float dsum = 0.f;

    for (int jb = 0; jb < 2048; jb += 32) {
        int k0 = jb + q * 8;                       // this lane's 8 j's
        uint32_t mbyte = adjr[k0 >> 3];
        float4 s2a = *reinterpret_cast<const float4*>(s2b + k0);
        float4 s2c = *reinterpret_cast<const float4*>(s2b + k0 + 4);
        float s2arr[8] = {s2a.x, s2a.y, s2a.z, s2a.w, s2c.x, s2c.y, s2c.z, s2c.w};

        bf16x8 afrag;
        #pragma unroll
        for (int j = 0; j < 8; ++j) {
            float e = s1v + s2arr[j];
            e = fmaxf(e, ALPHA * e);               // leakyrelu
            float p = ((mbyte >> j) & 1) ? __expf(e) : 0.0f;
            dsum += p;
            afrag[j] = f2bf(p);
        }

        const short* bp = whTb + k0;
        #pragma unroll
        for (int t = 0; t < 8; ++t) {
            bf16x8 bfrag = *reinterpret_cast<const bf16x8*>(bp + (size_t)(t * 16 + n) * 2048);
            acc[t] = __builtin_amdgcn_mfma_f32_16x16x32_bf16(afrag, bfrag, acc[t], 0, 0, 0);
        }
    }

    // row denominators: row m lives in lanes {m, m+16, m+32, m+48}
    dsum += __shfl_xor(dsum, 16);
    dsum += __shfl_xor(dsum, 32);
    float rd[4];
    #pragma unroll
    for (int r = 0; r < 4; ++r) rd[r] = 1.0f / __shfl(dsum, q * 4 + r);

    #pragma unroll
    for (int t = 0; t < 8; ++t)
        #pragma unroll
        for (int r = 0; r < 4; ++r) {
            size_t o = ((size_t)b * 2048 + ib + q * 4 + r) * 128 + t * 16 + n;
            out[o] = acc[t][r] * rd[r];
        }
}

// ---------------------------------------------------------------------------
extern "C" void kernel_launch(void* const* d_in, const int* in_sizes, int n_in,
                              void* d_out, int out_size, void* d_ws, size_t ws_size,
                              hipStream_t stream) {
    const float* h   = (const float*)d_in[0];   // [8][2048][128] f32
    const int*   adj = (const int*)d_in[1];     // [2048][2048] i32
    const float* W   = (const float*)d_in[2];   // [128][128] f32
    const float* a   = (const float*)d_in[3];   // [256][1] f32
    float* out = (float*)d_out;                 // [8][2048][128] f32

    char* ws = (char*)d_ws;
    short* whT = (short*)ws;                                  // 4 MB  bf16 WhT
    float* s1  = (float*)(ws + 4194304);                      // 64 KB
    float* s2  = (float*)(ws + 4259840);                      // 64 KB
    unsigned long long* bits = (unsigned long long*)(ws + 4325376); // 512 KB

    pack_adj_kernel<<<16384, 256, 0, stream>>>(adj, bits);
    wh_kernel<<<256, 256, 0, stream>>>(h, W, a, whT, s1, s2);
    attn_kernel<<<256, 256, 0, stream>>>(whT, s1, s2, (const uint8_t*)bits, out);
}

// Round 2
// 134.456 us; speedup vs baseline: 1.6939x; 1.6939x over previous
//
#include <hip/hip_runtime.h>
#include <hip/hip_bf16.h>
#include <stdint.h>

#define ALPHA 0.2f

typedef __attribute__((ext_vector_type(8))) short bf16x8;
typedef __attribute__((ext_vector_type(4))) float f32x4;

__device__ __forceinline__ short f2bf(float f) {
    union { float f; uint32_t u; } c; c.f = f;
    uint32_t u = c.u + 0x7FFF + ((c.u >> 16) & 1);   // round-to-nearest-even
    return (short)(u >> 16);
}

// ---------------------------------------------------------------------------
// Kernel 0: pack adj (int32 0/1, [2048][2048]) into bitmask, 1 bit per edge.
// ---------------------------------------------------------------------------
__global__ __launch_bounds__(256) void pack_adj_kernel(
        const int* __restrict__ adj, unsigned long long* __restrict__ bits) {
    int idx = blockIdx.x * 256 + threadIdx.x;
    int lane = threadIdx.x & 63;
    unsigned long long m = __ballot(adj[idx] > 0);
    if (lane == 0) bits[idx >> 6] = m;
}

// ---------------------------------------------------------------------------
// Kernel 1 (v2): Wh = h @ W; epilogue: s1/s2 and WhT_bf16 [b][f][j].
// Grid 512 x 256thr. Block = 32 rows (2 tiles of 16); wave = (tile, f-half):
// each wave computes 16 rows x 64 f -> 2x TLP vs v1 (2048 waves).
// ---------------------------------------------------------------------------
__global__ __launch_bounds__(256) void wh_kernel(
        const float* __restrict__ h, const float* __restrict__ W,
        const float* __restrict__ a, short* __restrict__ whT,
        float* __restrict__ s1g, float* __restrict__ s2g) {
    __shared__ short WT[128][136];        // W^T bf16 [f][k], 34816 B
    __shared__ float sred[4][2][16];      // per-wave partial s1/s2 per row
    __shared__ short tr[4][64][24];       // per-wave transpose scratch, 12 KB

    int tid = threadIdx.x;
    // cooperative transpose W (fp32 [k][f]) -> WT bf16 [f][k]
    #pragma unroll
    for (int it = 0; it < 16; ++it) {
        int idx = it * 256 + tid;
        int k  = idx >> 5;
        int f4 = (idx & 31) * 4;
        float4 w4 = reinterpret_cast<const float4*>(W)[idx];
        WT[f4 + 0][k] = f2bf(w4.x);
        WT[f4 + 1][k] = f2bf(w4.y);
        WT[f4 + 2][k] = f2bf(w4.z);
        WT[f4 + 3][k] = f2bf(w4.w);
    }
    __syncthreads();

    int wid = tid >> 6, lane = tid & 63;
    int q = lane >> 4, n = lane & 15;
    int tile = wid >> 1, fh = wid & 1;
    int rb = blockIdx.x * 32 + tile * 16;          // global row base (b*2048+j)
    int row = rb + n;

    f32x4 acc[4] = {};
    #pragma unroll
    for (int kc = 0; kc < 4; ++kc) {
        const float* hp = h + (size_t)row * 128 + kc * 32 + q * 8;
        float4 h0 = reinterpret_cast<const float4*>(hp)[0];
        float4 h1 = reinterpret_cast<const float4*>(hp)[1];
        bf16x8 afrag;
        afrag[0] = f2bf(h0.x); afrag[1] = f2bf(h0.y);
        afrag[2] = f2bf(h0.z); afrag[3] = f2bf(h0.w);
        afrag[4] = f2bf(h1.x); afrag[5] = f2bf(h1.y);
        afrag[6] = f2bf(h1.z); afrag[7] = f2bf(h1.w);
        #pragma unroll
        for (int u = 0; u < 4; ++u) {
            int t = fh * 4 + u;
            bf16x8 bfrag = *reinterpret_cast<const bf16x8*>(&WT[t * 16 + n][kc * 32 + q * 8]);
            acc[u] = __builtin_amdgcn_mfma_f32_16x16x32_bf16(afrag, bfrag, acc[u], 0, 0, 0);
        }
    }

    // ---- s1/s2 partial (this wave's 64 f), reduce over n, combine via LDS
    float p1[4] = {0.f, 0.f, 0.f, 0.f}, p2[4] = {0.f, 0.f, 0.f, 0.f};
    #pragma unroll
    for (int u = 0; u < 4; ++u) {
        int c = (fh * 4 + u) * 16 + n;
        float a1c = a[c], a2c = a[128 + c];
        #pragma unroll
        for (int r = 0; r < 4; ++r) {
            p1[r] += acc[u][r] * a1c;
            p2[r] += acc[u][r] * a2c;
        }
    }
    #pragma unroll
    for (int d = 1; d < 16; d <<= 1) {
        #pragma unroll
        for (int r = 0; r < 4; ++r) {
            p1[r] += __shfl_xor(p1[r], d);
            p2[r] += __shfl_xor(p2[r], d);
        }
    }
    if (n == 0) {
        #pragma unroll
        for (int r = 0; r < 4; ++r) {
            sred[wid][0][q * 4 + r] = p1[r];
            sred[wid][1][q * 4 + r] = p2[r];
        }
    }

    // ---- transpose epilogue: acc -> tr[wid] ([local f][j-in-tile])
    #pragma unroll
    for (int u = 0; u < 4; ++u)
        #pragma unroll
        for (int r = 0; r < 4; ++r)
            tr[wid][u * 16 + n][q * 4 + r] = f2bf(acc[u][r]);
    __syncthreads();

    if (fh == 0 && lane < 16) {
        float v1 = sred[wid][0][lane] + sred[wid + 1][0][lane];
        float v2 = sred[wid][1][lane] + sred[wid + 1][1][lane];
        s1g[rb + lane] = v1;
        s2g[rb + lane] = v2;
    }

    int bb = rb >> 11, jr = rb & 2047;
    int f = fh * 64 + lane;                        // this lane's global f
    bf16x8 v0 = *reinterpret_cast<const bf16x8*>(&tr[wid][lane][0]);
    bf16x8 v1 = *reinterpret_cast<const bf16x8*>(&tr[wid][lane][8]);
    size_t o = ((size_t)(bb * 128 + f) * 2048) + jr;
    *reinterpret_cast<bf16x8*>(whT + o)     = v0;  // j 0..7
    *reinterpret_cast<bf16x8*>(whT + o + 8) = v1;  // j 8..15
}

// ---------------------------------------------------------------------------
// Kernel 2 (v2): fused masked-softmax attention + PV.
// Grid 512 blocks (b, itile of 32 rows) x 512 threads (8 waves).
// Wave = 32 i-rows (two 16-row A-frags sharing B-frags) x j-slice of 256.
// Cross-wave combine of unnormalized acc via 32 KB LDS pairwise tree.
// ---------------------------------------------------------------------------
__global__ __launch_bounds__(512) void attn_kernel(
        const short* __restrict__ whT, const float* __restrict__ s1g,
        const float* __restrict__ s2g, const uint8_t* __restrict__ adjb,
        float* __restrict__ out) {
    __shared__ f32x4 cbuf[2][16][64];              // 32 KB combine buffers
    __shared__ float lds_ds[8][2][16];             // per-wave row denominators

    int wid = threadIdx.x >> 6, lane = threadIdx.x & 63;
    int q = lane >> 4, n = lane & 15;
    int b  = blockIdx.x >> 6;
    int ib = (blockIdx.x & 63) * 32;
    int rowA = ib + n, rowB = ib + 16 + n;

    float s1A = s1g[b * 2048 + rowA];
    float s1B = s1g[b * 2048 + rowB];
    const float*   s2b  = s2g + b * 2048;
    const short*   whTb = whT + (size_t)b * 128 * 2048;
    const uint8_t* adjA = adjb + (size_t)rowA * 256;
    const uint8_t* adjB = adjb + (size_t)rowB * 256;

    f32x4 accA[8] = {}, accB[8] = {};
    float dsA = 0.f, dsB = 0.f;
    int jbase = wid * 256;

    for (int c = 0; c < 8; ++c) {
        int k0 = jbase + c * 32 + q * 8;
        uint32_t mA = adjA[k0 >> 3];
        uint32_t mB = adjB[k0 >> 3];
        float4 s2a = *reinterpret_cast<const float4*>(s2b + k0);
        float4 s2c = *reinterpret_cast<const float4*>(s2b + k0 + 4);
        float s2arr[8] = {s2a.x, s2a.y, s2a.z, s2a.w, s2c.x, s2c.y, s2c.z, s2c.w};

        bf16x8 afA, afB;
        #pragma unroll
        for (int j = 0; j < 8; ++j) {
            float eA = s1A + s2arr[j];
            eA = fmaxf(eA, ALPHA * eA);
            float pA = ((mA >> j) & 1) ? __expf(eA) : 0.0f;
            dsA += pA; afA[j] = f2bf(pA);
            float eB = s1B + s2arr[j];
            eB = fmaxf(eB, ALPHA * eB);
            float pB = ((mB >> j) & 1) ? __expf(eB) : 0.0f;
            dsB += pB; afB[j] = f2bf(pB);
        }

        const short* bp = whTb + k0;
        #pragma unroll
        for (int t = 0; t < 8; ++t) {
            bf16x8 bf = *reinterpret_cast<const bf16x8*>(bp + (size_t)(t * 16 + n) * 2048);
            accA[t] = __builtin_amdgcn_mfma_f32_16x16x32_bf16(afA, bf, accA[t], 0, 0, 0);
            accB[t] = __builtin_amdgcn_mfma_f32_16x16x32_bf16(afB, bf, accB[t], 0, 0, 0);
        }
    }

    // intra-wave denominator reduce (row m lives in lanes m, m+16, m+32, m+48)
    dsA += __shfl_xor(dsA, 16); dsA += __shfl_xor(dsA, 32);
    dsB += __shfl_xor(dsB, 16); dsB += __shfl_xor(dsB, 32);
    if (q == 0) { lds_ds[wid][0][n] = dsA; lds_ds[wid][1][n] = dsB; }

    auto writeP = [&](int buf) {
        #pragma unroll
        for (int i = 0; i < 8; ++i) {
            cbuf[buf][i][lane]     = accA[i];
            cbuf[buf][8 + i][lane] = accB[i];
        }
    };
    auto addP = [&](int buf) {
        #pragma unroll
        for (int i = 0; i < 8; ++i) {
            accA[i] += cbuf[buf][i][lane];
            accB[i] += cbuf[buf][8 + i][lane];
        }
    };

    // pairwise tree: w0+=w4, w1+=w5; w2+=w6, w3+=w7; w0+=w2, w1+=w3; w0+=w1
    __syncthreads();
    if (wid == 4) writeP(0); else if (wid == 5) writeP(1);
    __syncthreads();
    if (wid == 0) addP(0); else if (wid == 1) addP(1);
    __syncthreads();
    if (wid == 6) writeP(0); else if (wid == 7) writeP(1);
    __syncthreads();
    if (wid == 2) addP(0); else if (wid == 3) addP(1);
    __syncthreads();
    if (wid == 2) writeP(0); else if (wid == 3) writeP(1);
    __syncthreads();
    if (wid == 0) addP(0); else if (wid == 1) addP(1);
    __syncthreads();
    if (wid == 1) writeP(0);
    __syncthreads();

    if (wid == 0) {
        addP(0);
        float dAt = 0.f, dBt = 0.f;
        #pragma unroll
        for (int w2 = 0; w2 < 8; ++w2) {
            dAt += lds_ds[w2][0][n];
            dBt += lds_ds[w2][1][n];
        }
        float rdA[4], rdB[4];
        #pragma unroll
        for (int r = 0; r < 4; ++r) {
            rdA[r] = 1.0f / __shfl(dAt, q * 4 + r);
            rdB[r] = 1.0f / __shfl(dBt, q * 4 + r);
        }
        size_t ob = ((size_t)b * 2048 + ib) * 128;
        #pragma unroll
        for (int t = 0; t < 8; ++t)
            #pragma unroll
            for (int r = 0; r < 4; ++r) {
                out[ob + (size_t)(q * 4 + r) * 128 + t * 16 + n]        = accA[t][r] * rdA[r];
                out[ob + (size_t)(16 + q * 4 + r) * 128 + t * 16 + n]   = accB[t][r] * rdB[r];
            }
    }
}

// ---------------------------------------------------------------------------
extern "C" void kernel_launch(void* const* d_in, const int* in_sizes, int n_in,
                              void* d_out, int out_size, void* d_ws, size_t ws_size,
                              hipStream_t stream) {
    const float* h   = (const float*)d_in[0];   // [8][2048][128] f32
    const int*   adj = (const int*)d_in[1];     // [2048][2048] i32
    const float* W   = (const float*)d_in[2];   // [128][128] f32
    const float* a   = (const float*)d_in[3];   // [256][1] f32
    float* out = (float*)d_out;                 // [8][2048][128] f32

    char* ws = (char*)d_ws;
    short* whT = (short*)ws;                                  // 4 MB  bf16 WhT
    float* s1  = (float*)(ws + 4194304);                      // 64 KB
    float* s2  = (float*)(ws + 4259840);                      // 64 KB
    unsigned long long* bits = (unsigned long long*)(ws + 4325376); // 512 KB

    pack_adj_kernel<<<16384, 256, 0, stream>>>(adj, bits);
    wh_kernel<<<512, 256, 0, stream>>>(h, W, a, whT, s1, s2);
    attn_kernel<<<512, 512, 0, stream>>>(whT, s1, s2, (const uint8_t*)bits, out);
}

// Round 3
// 127.133 us; speedup vs baseline: 1.7915x; 1.0576x over previous
//
#include <hip/hip_runtime.h>
#include <hip/hip_bf16.h>
#include <stdint.h>

#define ALPHA 0.2f

typedef __attribute__((ext_vector_type(8))) short bf16x8;
typedef __attribute__((ext_vector_type(4))) float f32x4;

__device__ __forceinline__ short f2bf(float f) {
    union { float f; uint32_t u; } c; c.f = f;
    uint32_t u = c.u + 0x7FFF + ((c.u >> 16) & 1);   // round-to-nearest-even
    return (short)(u >> 16);
}

// ---------------------------------------------------------------------------
// Kernel 0 (v2): pack adj into byte-masks (8 ints -> 1 byte per thread, no
// ballot). 2048 blocks x 256 thr. First 64 blocks also pre-transpose
// W (fp32 [k][f]) -> WTg (bf16 [f][k]) so wh_kernel needs no LDS staging.
// ---------------------------------------------------------------------------
__global__ __launch_bounds__(256) void pack_adj_kernel(
        const int* __restrict__ adj, uint8_t* __restrict__ bytes,
        const float* __restrict__ W, short* __restrict__ WTg) {
    int t = blockIdx.x * 256 + threadIdx.x;            // 524288 threads
    const int4* a4 = reinterpret_cast<const int4*>(adj) + (size_t)t * 2;
    int4 x0 = a4[0], x1 = a4[1];
    uint32_t m = 0;
    m |= (x0.x > 0) ? 1u   : 0u;  m |= (x0.y > 0) ? 2u   : 0u;
    m |= (x0.z > 0) ? 4u   : 0u;  m |= (x0.w > 0) ? 8u   : 0u;
    m |= (x1.x > 0) ? 16u  : 0u;  m |= (x1.y > 0) ? 32u  : 0u;
    m |= (x1.z > 0) ? 64u  : 0u;  m |= (x1.w > 0) ? 128u : 0u;
    bytes[t] = (uint8_t)m;

    if (blockIdx.x < 64) {                             // 16384 elems of W
        int idx = blockIdx.x * 256 + threadIdx.x;
        int k = idx >> 7, f = idx & 127;               // coalesced read of W
        WTg[f * 128 + k] = f2bf(W[k * 128 + f]);
    }
}

// ---------------------------------------------------------------------------
// Kernel 1 (v3): Wh = h @ W; epilogue: s1/s2 and WhT_bf16 [b][f][j].
// Grid 1024 x 256 thr. Block = 16 rows; wave w = 16 rows x 32 f
// (t-tiles 2w, 2w+1). B-frags read directly from WTg (L2-resident 32 KB).
// ---------------------------------------------------------------------------
__global__ __launch_bounds__(256) void wh_kernel(
        const float* __restrict__ h, const short* __restrict__ WTg,
        const float* __restrict__ a, short* __restrict__ whT,
        float* __restrict__ s1g, float* __restrict__ s2g) {
    __shared__ float sred[4][2][16];
    __shared__ short tr[4][32][24];

    int tid = threadIdx.x, wid = tid >> 6, lane = tid & 63;
    int q = lane >> 4, n = lane & 15;
    int rb = blockIdx.x * 16;                          // global row base
    int row = rb + n;

    f32x4 acc[2] = {};
    #pragma unroll
    for (int kc = 0; kc < 4; ++kc) {
        const float* hp = h + (size_t)row * 128 + kc * 32 + q * 8;
        float4 h0 = reinterpret_cast<const float4*>(hp)[0];
        float4 h1 = reinterpret_cast<const float4*>(hp)[1];
        bf16x8 afrag;
        afrag[0] = f2bf(h0.x); afrag[1] = f2bf(h0.y);
        afrag[2] = f2bf(h0.z); afrag[3] = f2bf(h0.w);
        afrag[4] = f2bf(h1.x); afrag[5] = f2bf(h1.y);
        afrag[6] = f2bf(h1.z); afrag[7] = f2bf(h1.w);
        #pragma unroll
        for (int u = 0; u < 2; ++u) {
            int t = wid * 2 + u;
            bf16x8 bfrag = *reinterpret_cast<const bf16x8*>(
                WTg + (t * 16 + n) * 128 + kc * 32 + q * 8);
            acc[u] = __builtin_amdgcn_mfma_f32_16x16x32_bf16(afrag, bfrag, acc[u], 0, 0, 0);
        }
    }

    // s1/s2 partials over this wave's 32 f
    float p1[4] = {0.f, 0.f, 0.f, 0.f}, p2[4] = {0.f, 0.f, 0.f, 0.f};
    #pragma unroll
    for (int u = 0; u < 2; ++u) {
        int c = (wid * 2 + u) * 16 + n;
        float a1c = a[c], a2c = a[128 + c];
        #pragma unroll
        for (int r = 0; r < 4; ++r) {
            p1[r] += acc[u][r] * a1c;
            p2[r] += acc[u][r] * a2c;
        }
    }
    #pragma unroll
    for (int d = 1; d < 16; d <<= 1) {
        #pragma unroll
        for (int r = 0; r < 4; ++r) {
            p1[r] += __shfl_xor(p1[r], d);
            p2[r] += __shfl_xor(p2[r], d);
        }
    }
    if (n == 0) {
        #pragma unroll
        for (int r = 0; r < 4; ++r) {
            sred[wid][0][q * 4 + r] = p1[r];
            sred[wid][1][q * 4 + r] = p2[r];
        }
    }

    // transpose this wave's 32f x 16j tile into LDS
    #pragma unroll
    for (int u = 0; u < 2; ++u)
        #pragma unroll
        for (int r = 0; r < 4; ++r)
            tr[wid][u * 16 + n][q * 4 + r] = f2bf(acc[u][r]);
    __syncthreads();

    if (wid == 0 && lane < 16) {
        float v1 = 0.f, v2 = 0.f;
        #pragma unroll
        for (int v = 0; v < 4; ++v) { v1 += sred[v][0][lane]; v2 += sred[v][1][lane]; }
        s1g[rb + lane] = v1;
        s2g[rb + lane] = v2;
    }

    int bb = rb >> 11, jr = rb & 2047;
    int fl = lane & 31, jh = lane >> 5;                // local f, j-half
    bf16x8 v = *reinterpret_cast<const bf16x8*>(&tr[wid][fl][jh * 8]);
    int f = wid * 32 + fl;
    *reinterpret_cast<bf16x8*>(whT + ((size_t)(bb * 128 + f) * 2048) + jr + jh * 8) = v;
}

// ---------------------------------------------------------------------------
// Kernel 2 (v3): fused masked-softmax attention + PV.
// Grid 512 blocks (b, itile of 32 rows) x 512 threads (8 waves, j-split 8).
// Combine: 2-round flat LDS reduce (64 KB buffer, 3 barriers), epilogue
// 8-way parallel: wave w reduces & stores acc-index w.
// ---------------------------------------------------------------------------
__global__ __launch_bounds__(512) void attn_kernel(
        const short* __restrict__ whT, const float* __restrict__ s1g,
        const float* __restrict__ s2g, const uint8_t* __restrict__ adjb,
        float* __restrict__ out) {
    __shared__ f32x4 buf[8][8][64];                    // 64 KB combine buffer
    __shared__ float lds_ds[8][2][16];                 // per-wave denominators

    int wid = threadIdx.x >> 6, lane = threadIdx.x & 63;
    int q = lane >> 4, n = lane & 15;
    int b  = blockIdx.x >> 6;
    int ib = (blockIdx.x & 63) * 32;
    int rowA = ib + n, rowB = ib + 16 + n;

    float s1A = s1g[b * 2048 + rowA];
    float s1B = s1g[b * 2048 + rowB];
    const float*   s2b  = s2g + b * 2048;
    const short*   whTb = whT + (size_t)b * 262144;
    const uint8_t* adjA = adjb + (size_t)rowA * 256;
    const uint8_t* adjB = adjb + (size_t)rowB * 256;

    f32x4 accA[8] = {}, accB[8] = {};
    float dsA = 0.f, dsB = 0.f;
    int jbase = wid * 256;

    for (int c = 0; c < 8; ++c) {
        int k0 = jbase + c * 32 + q * 8;
        uint32_t mA = adjA[k0 >> 3];
        uint32_t mB = adjB[k0 >> 3];
        float4 s2a = *reinterpret_cast<const float4*>(s2b + k0);
        float4 s2c = *reinterpret_cast<const float4*>(s2b + k0 + 4);
        float s2arr[8] = {s2a.x, s2a.y, s2a.z, s2a.w, s2c.x, s2c.y, s2c.z, s2c.w};

        bf16x8 afA, afB;
        #pragma unroll
        for (int j = 0; j < 8; ++j) {
            float eA = s1A + s2arr[j];
            eA = fmaxf(eA, ALPHA * eA);
            float pA = ((mA >> j) & 1) ? __expf(eA) : 0.0f;
            dsA += pA; afA[j] = f2bf(pA);
            float eB = s1B + s2arr[j];
            eB = fmaxf(eB, ALPHA * eB);
            float pB = ((mB >> j) & 1) ? __expf(eB) : 0.0f;
            dsB += pB; afB[j] = f2bf(pB);
        }

        const short* bp = whTb + k0;
        #pragma unroll
        for (int t = 0; t < 8; ++t) {
            bf16x8 bf = *reinterpret_cast<const bf16x8*>(bp + (size_t)(t * 16 + n) * 2048);
            accA[t] = __builtin_amdgcn_mfma_f32_16x16x32_bf16(afA, bf, accA[t], 0, 0, 0);
            accB[t] = __builtin_amdgcn_mfma_f32_16x16x32_bf16(afB, bf, accB[t], 0, 0, 0);
        }
    }

    // intra-wave denominator reduce; row m lives in lanes m, m+16, m+32, m+48
    dsA += __shfl_xor(dsA, 16); dsA += __shfl_xor(dsA, 32);
    dsB += __shfl_xor(dsB, 16); dsB += __shfl_xor(dsB, 32);
    if (q == 0) { lds_ds[wid][0][n] = dsA; lds_ds[wid][1][n] = dsB; }

    // ---- round A: all waves stage accA; wave w reduces acc-index w
    #pragma unroll
    for (int i = 0; i < 8; ++i) buf[wid][i][lane] = accA[i];
    __syncthreads();

    f32x4 sA = buf[0][wid][lane];
    #pragma unroll
    for (int v = 1; v < 8; ++v) sA += buf[v][wid][lane];

    float dAt = 0.f, dBt = 0.f;
    #pragma unroll
    for (int v = 0; v < 8; ++v) { dAt += lds_ds[v][0][n]; dBt += lds_ds[v][1][n]; }
    float rdA[4], rdB[4];
    #pragma unroll
    for (int r = 0; r < 4; ++r) {
        rdA[r] = 1.0f / __shfl(dAt, q * 4 + r);
        rdB[r] = 1.0f / __shfl(dBt, q * 4 + r);
    }

    size_t ob = ((size_t)b * 2048 + ib) * 128;
    #pragma unroll
    for (int r = 0; r < 4; ++r)
        out[ob + (size_t)(q * 4 + r) * 128 + wid * 16 + n] = sA[r] * rdA[r];
    __syncthreads();

    // ---- round B
    #pragma unroll
    for (int i = 0; i < 8; ++i) buf[wid][i][lane] = accB[i];
    __syncthreads();

    f32x4 sB = buf[0][wid][lane];
    #pragma unroll
    for (int v = 1; v < 8; ++v) sB += buf[v][wid][lane];
    #pragma unroll
    for (int r = 0; r < 4; ++r)
        out[ob + (size_t)(16 + q * 4 + r) * 128 + wid * 16 + n] = sB[r] * rdB[r];
}

// ---------------------------------------------------------------------------
extern "C" void kernel_launch(void* const* d_in, const int* in_sizes, int n_in,
                              void* d_out, int out_size, void* d_ws, size_t ws_size,
                              hipStream_t stream) {
    const float* h   = (const float*)d_in[0];   // [8][2048][128] f32
    const int*   adj = (const int*)d_in[1];     // [2048][2048] i32
    const float* W   = (const float*)d_in[2];   // [128][128] f32
    const float* a   = (const float*)d_in[3];   // [256][1] f32
    float* out = (float*)d_out;                 // [8][2048][128] f32

    char* ws = (char*)d_ws;
    short* whT = (short*)ws;                                  // 4 MB  bf16 WhT
    float* s1  = (float*)(ws + 4194304);                      // 64 KB
    float* s2  = (float*)(ws + 4259840);                      // 64 KB
    uint8_t* bytes = (uint8_t*)(ws + 4325376);                // 512 KB

    // WT scratch lives in the tail of d_out (32 KB); wh reads it before
    // attn overwrites the whole of d_out. Same-stream ordering makes it safe.
    short* WTg = (short*)d_out + (4194304 - 16384);

    pack_adj_kernel<<<2048, 256, 0, stream>>>(adj, bytes, W, WTg);
    wh_kernel<<<1024, 256, 0, stream>>>(h, WTg, a, whT, s1, s2);
    attn_kernel<<<512, 512, 0, stream>>>(whT, s1, s2, bytes, out);
}